// Round 18
// baseline (344.125 us; speedup 1.0000x reference)
//
#include <hip/hip_runtime.h>
#include <hip/hip_bf16.h>

#define RFn 500000
#define F1n 256
#define NFn 128
#define RAn 50000
#define LN_EPSn 1e-5f
#define RECB 256          // record: 128 bf16 = 2 full cache lines, 256B-aligned
#define NTILE2 (RFn / 32) // 15625 32-row tiles (RFn % 32 == 0: all full)
#define GRID8 2048        // persistent featw8 blocks
#define ROWPAD 1040       // LDS bytes per X row (1024 + 16 -> 2-way banks, free)
#define SCB 256
#define SCG ((RAn + SCB - 1) / SCB)  // 196

typedef float f32x4 __attribute__((ext_vector_type(4)));
typedef short short8 __attribute__((ext_vector_type(8)));

__device__ __forceinline__ short f2bf(float f) {
  __hip_bfloat16 h = __float2bfloat16(f);  // RNE
  return __builtin_bit_cast(short, h);
}

__device__ __forceinline__ void gload_lds16(const void* g, void* l) {
  __builtin_amdgcn_global_load_lds(
      (const __attribute__((address_space(1))) void*)g,
      (__attribute__((address_space(3))) void*)l, 16, 0, 0);
}

// ---------------------------------------------------------------------------
// Pack W_feat (256x128 f32) into MFMA B-frag image: frag (s,c), lane l:
// col = c*16+(l&15), k = s*32+(l>>4)*8+i  (8 bf16 per lane).
// ---------------------------------------------------------------------------
__global__ void prep_kernel(const float* __restrict__ Wf, short* __restrict__ frag) {
  int p = blockIdx.x * blockDim.x + threadIdx.x;  // 0..4095
  if (p >= 4096) return;
  int f = p >> 6, l = p & 63;
  int s = f >> 3, c = f & 7;
  int col = c * 16 + (l & 15);
  int k0 = s * 32 + ((l >> 4) << 3);
  short8 v;
#pragma unroll
  for (int i = 0; i < 8; ++i) v[i] = f2bf(Wf[(k0 + i) * NFn + col]);
  *(short8*)(frag + (size_t)p * 8) = v;
}

__global__ void hist_kernel(const int* __restrict__ ri, int* __restrict__ hist) {
  int i = blockIdx.x * 256 + threadIdx.x;
  if (i < RFn) atomicAdd(&hist[ri[i]], 1);
}

__global__ __launch_bounds__(256) void scanA_kernel(const int* __restrict__ hist,
                                                    int* __restrict__ T,
                                                    int* __restrict__ bsum) {
  __shared__ int ls[256];
  const int t = threadIdx.x, idx = blockIdx.x * 256 + t;
  const int v = (idx < RAn) ? hist[idx] : 0;
  ls[t] = v;
  __syncthreads();
  for (int off = 1; off < 256; off <<= 1) {
    int add = (t >= off) ? ls[t - off] : 0;
    __syncthreads();
    ls[t] += add;
    __syncthreads();
  }
  if (idx < RAn) T[idx] = ls[t] - v;
  if (t == 255) bsum[blockIdx.x] = ls[255];
}

__global__ __launch_bounds__(256) void scanB_kernel(int* __restrict__ bsum,
                                                    int* __restrict__ boff) {
  __shared__ int ls[256];
  const int t = threadIdx.x;
  const int v = (t < SCG) ? bsum[t] : 0;
  ls[t] = v;
  __syncthreads();
  for (int off = 1; off < 256; off <<= 1) {
    int add = (t >= off) ? ls[t - off] : 0;
    __syncthreads();
    ls[t] += add;
    __syncthreads();
  }
  if (t < SCG) boff[t] = ls[t] - v;
}

__global__ __launch_bounds__(256) void scanC_kernel(const int* __restrict__ T,
                                                    const int* __restrict__ boff,
                                                    int* __restrict__ rowstart,
                                                    int* __restrict__ cursor) {
  const int idx = blockIdx.x * 256 + threadIdx.x;
  if (idx < RAn) {
    int v = T[idx] + boff[blockIdx.x];
    rowstart[idx] = v;
    cursor[idx] = v;
  }
  if (idx == 0) rowstart[RAn] = RFn;
}

// inv[i] = sorted position of original row i (segment-major order)
__global__ void scatter_kernel(const int* __restrict__ ri, int* __restrict__ cursor,
                               int* __restrict__ inv) {
  int i = blockIdx.x * 256 + threadIdx.x;
  if (i < RFn) inv[i] = atomicAdd(&cursor[ri[i]], 1);
}

// ---------------------------------------------------------------------------
// featw8 = r15's featw5 + persistent blocks + W-IN-REGISTERS. Each wave's
// col-half of W (32 frags = 128 VGPR) is loaded ONCE from L2 and reused
// across ~7.6 tiles -> the per-tile loop has ZERO B-operand loads (the
// suspected exposed-latency term at 2 waves/SIMD). Geometry, staging,
// epilogue, record format identical to r15 (best measured, 295.9).
// ---------------------------------------------------------------------------
__global__ __launch_bounds__(128) void featw8_kernel(
    const float* __restrict__ X, const short* __restrict__ fragWS,
    const float* __restrict__ Wa, const float* __restrict__ ba,
    const float* __restrict__ bfeat, const float* __restrict__ gamma,
    const float* __restrict__ beta, const int* __restrict__ inv,
    char* __restrict__ buf, float* __restrict__ wbuf) {
  __shared__ __attribute__((aligned(16))) char lt[32 * ROWPAD];  // 33280 B
  __shared__ float sLN[2][32][2];                                // 512 B

  const int tid = threadIdx.x;
  const int lane = tid & 63;
  const int wv = tid >> 6;     // wave = col half
  const int colb = lane & 15;  // row-in-row-tile for compute
  const int kg = lane >> 4;

  // -------- W half in registers (loaded once; 32 x short8 = 128 VGPR) ----
  short8 wreg[32];
#pragma unroll
  for (int s = 0; s < 8; ++s)
#pragma unroll
    for (int cc = 0; cc < 4; ++cc)
      wreg[s * 4 + cc] =
          *(const short8*)(fragWS + (((s * 8 + wv * 4 + cc) * 64 + lane) * 8));

  // per-lane coefs for my col half: ct = wv*4+cc, col = ct*16+colb
  float g_r[4], be_r[4], bi_r[4];
#pragma unroll
  for (int cc = 0; cc < 4; ++cc) {
    const int col = (wv * 4 + cc) * 16 + colb;
    g_r[cc] = gamma[col];
    be_r[cc] = beta[col];
    bi_r[cc] = bfeat[col];
  }
  const float batn = ba[0];

  for (int t = blockIdx.x; t < NTILE2; t += GRID8) {
    // -------- stage my 16 rows (async, no VGPR round-trip) --------
    {
      const float* xr = X + (size_t)t * 32 * F1n;
#pragma unroll
      for (int r = 0; r < 16; ++r) {
        const int rr = wv * 16 + r;
        gload_lds16(xr + rr * F1n + lane * 4, &lt[rr * ROWPAD]);
      }
    }
    __syncthreads();  // [A] staging complete (each wave drains own vmcnt)

    // -------- GEMM over K=256: 4 col-tiles x 2 row-tiles, W from regs ----
    f32x4 acc[2][4];
#pragma unroll
    for (int rt = 0; rt < 2; ++rt)
#pragma unroll
      for (int cc = 0; cc < 4; ++cc) acc[rt][cc] = (f32x4)(0.0f);
    float logit[2] = {0.f, 0.f};

#pragma unroll
    for (int s = 0; s < 8; ++s) {
      const float4 wa0 = *(const float4*)(Wa + s * 32 + kg * 8);
      const float4 wa1 = *(const float4*)(Wa + s * 32 + kg * 8 + 4);
#pragma unroll
      for (int rt = 0; rt < 2; ++rt) {
        const char* xrow = lt + (rt * 16 + colb) * ROWPAD + s * 128 + kg * 32;
        const float4 x0 = *(const float4*)(xrow);
        const float4 x1 = *(const float4*)(xrow + 16);
        float a0 = fmaxf(x0.x, 0.01f * x0.x);
        float a1 = fmaxf(x0.y, 0.01f * x0.y);
        float a2 = fmaxf(x0.z, 0.01f * x0.z);
        float a3 = fmaxf(x0.w, 0.01f * x0.w);
        float a4 = fmaxf(x1.x, 0.01f * x1.x);
        float a5 = fmaxf(x1.y, 0.01f * x1.y);
        float a6 = fmaxf(x1.z, 0.01f * x1.z);
        float a7 = fmaxf(x1.w, 0.01f * x1.w);
        logit[rt] += a0 * wa0.x + a1 * wa0.y + a2 * wa0.z + a3 * wa0.w +
                     a4 * wa1.x + a5 * wa1.y + a6 * wa1.z + a7 * wa1.w;
        short8 af;
        af[0] = f2bf(a0); af[1] = f2bf(a1); af[2] = f2bf(a2); af[3] = f2bf(a3);
        af[4] = f2bf(a4); af[5] = f2bf(a5); af[6] = f2bf(a6); af[7] = f2bf(a7);
#pragma unroll
        for (int cc = 0; cc < 4; ++cc)
          acc[rt][cc] = __builtin_amdgcn_mfma_f32_16x16x32_bf16(
              af, wreg[s * 4 + cc], acc[rt][cc], 0, 0, 0);
      }
    }

    // -------- per row-tile: wexp, LN partials --------
    float wexp[2];
    float s1v[2][4], s2v[2][4];
#pragma unroll
    for (int rt = 0; rt < 2; ++rt) {
      float lg = logit[rt];
      lg += __shfl_xor(lg, 16);
      lg += __shfl_xor(lg, 32);
      wexp[rt] = __expf(lg + batn);
      if (wv == 0 && lane < 16) wbuf[inv[t * 32 + rt * 16 + colb]] = wexp[rt];

#pragma unroll
      for (int reg = 0; reg < 4; ++reg) {
        s1v[rt][reg] = 0.f;
        s2v[rt][reg] = 0.f;
      }
#pragma unroll
      for (int cc = 0; cc < 4; ++cc)
#pragma unroll
        for (int reg = 0; reg < 4; ++reg) {
          const float v = acc[rt][cc][reg] + bi_r[cc];
          acc[rt][cc][reg] = v;
          s1v[rt][reg] += v;
          s2v[rt][reg] += v * v;
        }
#pragma unroll
      for (int off = 1; off <= 8; off <<= 1)
#pragma unroll
        for (int reg = 0; reg < 4; ++reg) {
          s1v[rt][reg] += __shfl_xor(s1v[rt][reg], off);
          s2v[rt][reg] += __shfl_xor(s2v[rt][reg], off);
        }
      if (colb == 0) {
#pragma unroll
        for (int reg = 0; reg < 4; ++reg) {
          sLN[wv][rt * 16 + kg * 4 + reg][0] = s1v[rt][reg];
          sLN[wv][rt * 16 + kg * 4 + reg][1] = s2v[rt][reg];
        }
      }
    }
    __syncthreads();  // [B] partials ready; both waves done reading X from lt

    // -------- finish LN, write feat*w record image into dead lt --------
#pragma unroll
    for (int rt = 0; rt < 2; ++rt) {
      float w4[4];
#pragma unroll
      for (int reg = 0; reg < 4; ++reg) w4[reg] = __shfl(wexp[rt], kg * 4 + reg);
#pragma unroll
      for (int reg = 0; reg < 4; ++reg) {
        const int row = rt * 16 + kg * 4 + reg;
        const float s1 = s1v[rt][reg] + sLN[wv ^ 1][row][0];
        const float s2 = s2v[rt][reg] + sLN[wv ^ 1][row][1];
        const float mu = s1 * (1.0f / NFn);
        const float var = s2 * (1.0f / NFn) - mu * mu;
        const float rs = rsqrtf(var + LN_EPSn);
#pragma unroll
        for (int cc = 0; cc < 4; ++cc) {
          const float feat = (acc[rt][cc][reg] - mu) * rs * g_r[cc] + be_r[cc];
          ((short*)lt)[row * 136 + (wv * 4 + cc) * 16 + colb] =
              f2bf(feat * w4[reg]);  // 272B LDS row stride (bank spread)
        }
      }
    }
    __syncthreads();  // [C] full records ready

    // -------- 256B-aligned record stores (4 lanes x 64B per row) --------
    {
      const int row = tid >> 2;  // 0..31
      const int p = tid & 3;     // 64B chunk
      const int pos = inv[t * 32 + row];
      const char* src = lt + row * 272 + p * 64;
      char* dst = buf + (size_t)pos * RECB + p * 64;
      int4 v0 = *(const int4*)(src);
      int4 v1 = *(const int4*)(src + 16);
      int4 v2 = *(const int4*)(src + 32);
      int4 v3 = *(const int4*)(src + 48);
      *(int4*)(dst) = v0;
      *(int4*)(dst + 16) = v1;
      *(int4*)(dst + 32) = v2;
      *(int4*)(dst + 48) = v3;
    }
    __syncthreads();  // [D] record ds_reads done before next tile's staging
  }
}

// ---------------------------------------------------------------------------
// reduce: one wave per segment; 256B records + compact wbuf. Writes every
// segment (zeros for empty) so no out-memset is needed.
// ---------------------------------------------------------------------------
__global__ __launch_bounds__(256) void reduce_kernel(
    const char* __restrict__ buf, const float* __restrict__ wbuf,
    const int* __restrict__ rowstart, float* __restrict__ out) {
  const int lane = threadIdx.x & 63;
  const int seg = blockIdx.x * 4 + (threadIdx.x >> 6);
  if (seg >= RAn) return;
  const int rb = rowstart[seg], re = rowstart[seg + 1];
  float a0 = 0.f, a1 = 0.f, wsum = 0.f;
  for (int p = rb; p < re; ++p) {
    const char* rec = buf + (size_t)p * RECB;
    unsigned v = *(const unsigned*)(rec + lane * 4);
    a0 += __builtin_bit_cast(float, v << 16);
    a1 += __builtin_bit_cast(float, v & 0xffff0000u);
    wsum += wbuf[p];
  }
  float2 o;
  if (re > rb) {
    o.x = a0 / wsum;
    o.y = a1 / wsum;
  } else {
    o.x = 0.f;
    o.y = 0.f;
  }
  *(float2*)(out + (size_t)seg * NFn + lane * 2) = o;
}

// ---------------------------------------------------------------------------
// Fallback path (small ws): round-1 atomic kernel, known-good.
// ---------------------------------------------------------------------------
__global__ __launch_bounds__(256) void main_atomic(
    const float* __restrict__ X, const short* __restrict__ fragWS,
    const float* __restrict__ Wa, const float* __restrict__ ba,
    const float* __restrict__ bfeat, const float* __restrict__ gamma,
    const float* __restrict__ beta, const int* __restrict__ res_index,
    float* __restrict__ Nacc, float* __restrict__ D) {
  __shared__ short sB[4096 * 8];
  const int tid = threadIdx.x;
  {
    const int4* src = (const int4*)fragWS;
    int4* dst = (int4*)sB;
#pragma unroll 4
    for (int i = tid; i < 4096; i += 256) dst[i] = src[i];
  }
  __syncthreads();
  const int lane = tid & 63;
  const int wv = tid >> 6;
  const int rowbase = blockIdx.x * 128 + wv * 32;
  const int colb = lane & 15;
  const int kg = lane >> 4;
  float g_r[8], be_r[8], bi_r[8];
#pragma unroll
  for (int c = 0; c < 8; ++c) {
    int col = c * 16 + colb;
    g_r[c] = gamma[col];
    be_r[c] = beta[col];
    bi_r[c] = bfeat[col];
  }
  const float batn = ba[0];
  f32x4 acc[2][8];
#pragma unroll
  for (int rt = 0; rt < 2; ++rt)
#pragma unroll
    for (int c = 0; c < 8; ++c) acc[rt][c] = (f32x4)(0.0f);
  float logit[2] = {0.f, 0.f};
  int gr0 = rowbase + colb;
  int gr1 = gr0 + 16;
  long r0 = (gr0 < RFn) ? gr0 : (RFn - 1);
  long r1 = (gr1 < RFn) ? gr1 : (RFn - 1);
  const float* xp0 = X + r0 * F1n + kg * 8;
  const float* xp1 = X + r1 * F1n + kg * 8;
#pragma unroll
  for (int s = 0; s < 8; ++s) {
    short8 bfr[8];
#pragma unroll
    for (int c = 0; c < 8; ++c)
      bfr[c] = *(const short8*)(sB + (((s * 8 + c) * 64 + lane) * 8));
    const float4 wa0 = *(const float4*)(Wa + s * 32 + kg * 8);
    const float4 wa1 = *(const float4*)(Wa + s * 32 + kg * 8 + 4);
#pragma unroll
    for (int rt = 0; rt < 2; ++rt) {
      const float* xp = rt ? xp1 : xp0;
      const float4 x0 = *(const float4*)(xp + s * 32);
      const float4 x1 = *(const float4*)(xp + s * 32 + 4);
      float a0 = fmaxf(x0.x, 0.01f * x0.x);
      float a1 = fmaxf(x0.y, 0.01f * x0.y);
      float a2 = fmaxf(x0.z, 0.01f * x0.z);
      float a3 = fmaxf(x0.w, 0.01f * x0.w);
      float a4 = fmaxf(x1.x, 0.01f * x1.x);
      float a5 = fmaxf(x1.y, 0.01f * x1.y);
      float a6 = fmaxf(x1.z, 0.01f * x1.z);
      float a7 = fmaxf(x1.w, 0.01f * x1.w);
      logit[rt] += a0 * wa0.x + a1 * wa0.y + a2 * wa0.z + a3 * wa0.w +
                   a4 * wa1.x + a5 * wa1.y + a6 * wa1.z + a7 * wa1.w;
      short8 af;
      af[0] = f2bf(a0); af[1] = f2bf(a1); af[2] = f2bf(a2); af[3] = f2bf(a3);
      af[4] = f2bf(a4); af[5] = f2bf(a5); af[6] = f2bf(a6); af[7] = f2bf(a7);
#pragma unroll
      for (int c = 0; c < 8; ++c)
        acc[rt][c] = __builtin_amdgcn_mfma_f32_16x16x32_bf16(af, bfr[c],
                                                             acc[rt][c], 0, 0, 0);
    }
  }
#pragma unroll
  for (int rt = 0; rt < 2; ++rt) {
    float lg = logit[rt];
    lg += __shfl_xor(lg, 16);
    lg += __shfl_xor(lg, 32);
    const float wexp = __expf(lg + batn);
    const int gr = rowbase + rt * 16 + colb;
    const int seg = res_index[(gr < RFn) ? gr : (RFn - 1)];
    if (lane < 16 && gr < RFn) atomicAdd(&D[seg], wexp);
    float w4[4];
    int s4[4], v4[4];
#pragma unroll
    for (int reg = 0; reg < 4; ++reg) {
      int srcl = kg * 4 + reg;
      w4[reg] = __shfl(wexp, srcl);
      s4[reg] = __shfl(seg, srcl);
      v4[reg] = (rowbase + rt * 16 + srcl) < RFn;
    }
    float s1v[4] = {0.f, 0.f, 0.f, 0.f}, s2v[4] = {0.f, 0.f, 0.f, 0.f};
#pragma unroll
    for (int c = 0; c < 8; ++c)
#pragma unroll
      for (int reg = 0; reg < 4; ++reg) {
        float t2 = acc[rt][c][reg] + bi_r[c];
        acc[rt][c][reg] = t2;
        s1v[reg] += t2;
        s2v[reg] += t2 * t2;
      }
#pragma unroll
    for (int off = 1; off <= 8; off <<= 1)
#pragma unroll
      for (int reg = 0; reg < 4; ++reg) {
        s1v[reg] += __shfl_xor(s1v[reg], off);
        s2v[reg] += __shfl_xor(s2v[reg], off);
      }
    float mu[4], rs[4];
#pragma unroll
    for (int reg = 0; reg < 4; ++reg) {
      mu[reg] = s1v[reg] * (1.0f / NFn);
      float var = s2v[reg] * (1.0f / NFn) - mu[reg] * mu[reg];
      rs[reg] = rsqrtf(var + LN_EPSn);
    }
#pragma unroll
    for (int c = 0; c < 8; ++c)
#pragma unroll
      for (int reg = 0; reg < 4; ++reg) {
        if (v4[reg]) {
          float feat = (acc[rt][c][reg] - mu[reg]) * rs[reg] * g_r[c] + be_r[c];
          atomicAdd(Nacc + (size_t)s4[reg] * NFn + c * 16 + colb, feat * w4[reg]);
        }
      }
  }
}

__global__ void div_kernel(float* __restrict__ out, const float* __restrict__ D) {
  int i = blockIdx.x * 256 + threadIdx.x;
  if (i < RAn * NFn) {
    float d = D[i >> 7];
    out[i] = (d > 0.f) ? out[i] / d : 0.f;
  }
}

extern "C" void kernel_launch(void* const* d_in, const int* in_sizes, int n_in,
                              void* d_out, int out_size, void* d_ws, size_t ws_size,
                              hipStream_t stream) {
  const float* X = (const float*)d_in[0];
  const float* Wf = (const float*)d_in[1];
  const float* bfeat = (const float*)d_in[2];
  const float* gamma = (const float*)d_in[3];
  const float* beta = (const float*)d_in[4];
  const float* Wa = (const float*)d_in[5];
  const float* ba = (const float*)d_in[6];
  const int* ri = (const int*)d_in[7];
  float* out = (float*)d_out;

  char* ws = (char*)d_ws;
  short* frag = (short*)ws;              // 65,536 B
  int* hist = (int*)(ws + 65536);        // 200,000 B
  int* T = (int*)(ws + 265536);          // 200,000 B
  int* bsum = (int*)(ws + 465536);       // 784 B
  int* boff = (int*)(ws + 466320);       // 784 B
  int* rowstart = (int*)(ws + 467104);   // 200,004 B
  int* cursor = (int*)(ws + 667108);     // 200,000 B
  int* inv = (int*)(ws + 867108);        // 2,000,000 B
  float* wbuf = (float*)(ws + 2867108);  // 2,000,000 B
  char* buf = ws + 4867328;              // 256-aligned; 128,000,000 B
  const size_t NEED = 4867328ULL + (size_t)RFn * RECB;  // ~132.9 MB

  prep_kernel<<<16, 256, 0, stream>>>(Wf, frag);

  if (ws_size >= NEED) {
    hipMemsetAsync(hist, 0, (size_t)RAn * sizeof(int), stream);
    hist_kernel<<<(RFn + 255) / 256, 256, 0, stream>>>(ri, hist);
    scanA_kernel<<<SCG, 256, 0, stream>>>(hist, T, bsum);
    scanB_kernel<<<1, 256, 0, stream>>>(bsum, boff);
    scanC_kernel<<<SCG, 256, 0, stream>>>(T, boff, rowstart, cursor);
    scatter_kernel<<<(RFn + 255) / 256, 256, 0, stream>>>(ri, cursor, inv);
    featw8_kernel<<<GRID8, 128, 0, stream>>>(X, frag, Wa, ba, bfeat, gamma,
                                             beta, inv, buf, wbuf);
    reduce_kernel<<<(RAn + 3) / 4, 256, 0, stream>>>(buf, wbuf, rowstart, out);
  } else {
    float* D = (float*)(ws + 65536);
    hipMemsetAsync(out, 0, (size_t)RAn * NFn * sizeof(float), stream);
    hipMemsetAsync(D, 0, (size_t)RAn * sizeof(float), stream);
    main_atomic<<<(RFn + 127) / 128, 256, 0, stream>>>(X, frag, Wa, ba, bfeat,
                                                       gamma, beta, ri, out, D);
    div_kernel<<<(RAn * NFn + 255) / 256, 256, 0, stream>>>(out, D);
  }
}

// Round 19
// 297.006 us; speedup vs baseline: 1.1586x; 1.1586x over previous
//
#include <hip/hip_runtime.h>
#include <hip/hip_bf16.h>

#define RFn 500000
#define F1n 256
#define NFn 128
#define RAn 50000
#define LN_EPSn 1e-5f
#define RECB 256          // record: 128 bf16 = 2 full cache lines, 256B-aligned
#define NTILE2 (RFn / 32) // 15625 32-row blocks (RFn % 32 == 0: all full)
#define ROWPAD 1040       // LDS bytes per X row (1024 + 16 -> 2-way banks, free)
#define SCB 256
#define SCG ((RAn + SCB - 1) / SCB)  // 196

typedef float f32x4 __attribute__((ext_vector_type(4)));
typedef short short8 __attribute__((ext_vector_type(8)));

__device__ __forceinline__ short f2bf(float f) {
  __hip_bfloat16 h = __float2bfloat16(f);  // RNE
  return __builtin_bit_cast(short, h);
}

__device__ __forceinline__ void gload_lds16(const void* g, void* l) {
  __builtin_amdgcn_global_load_lds(
      (const __attribute__((address_space(1))) void*)g,
      (__attribute__((address_space(3))) void*)l, 16, 0, 0);
}

// ---------------------------------------------------------------------------
// Pack W_feat (256x128 f32) into MFMA B-frag image: frag (s,c), lane l:
// col = c*16+(l&15), k = s*32+(l>>4)*8+i  (8 bf16 per lane).
// ---------------------------------------------------------------------------
__global__ void prep_kernel(const float* __restrict__ Wf, short* __restrict__ frag) {
  int p = blockIdx.x * blockDim.x + threadIdx.x;  // 0..4095
  if (p >= 4096) return;
  int f = p >> 6, l = p & 63;
  int s = f >> 3, c = f & 7;
  int col = c * 16 + (l & 15);
  int k0 = s * 32 + ((l >> 4) << 3);
  short8 v;
#pragma unroll
  for (int i = 0; i < 8; ++i) v[i] = f2bf(Wf[(k0 + i) * NFn + col]);
  *(short8*)(frag + (size_t)p * 8) = v;
}

__global__ void hist_kernel(const int* __restrict__ ri, int* __restrict__ hist) {
  int i = blockIdx.x * 256 + threadIdx.x;
  if (i < RFn) atomicAdd(&hist[ri[i]], 1);
}

__global__ __launch_bounds__(256) void scanA_kernel(const int* __restrict__ hist,
                                                    int* __restrict__ T,
                                                    int* __restrict__ bsum) {
  __shared__ int ls[256];
  const int t = threadIdx.x, idx = blockIdx.x * 256 + t;
  const int v = (idx < RAn) ? hist[idx] : 0;
  ls[t] = v;
  __syncthreads();
  for (int off = 1; off < 256; off <<= 1) {
    int add = (t >= off) ? ls[t - off] : 0;
    __syncthreads();
    ls[t] += add;
    __syncthreads();
  }
  if (idx < RAn) T[idx] = ls[t] - v;
  if (t == 255) bsum[blockIdx.x] = ls[255];
}

__global__ __launch_bounds__(256) void scanB_kernel(int* __restrict__ bsum,
                                                    int* __restrict__ boff) {
  __shared__ int ls[256];
  const int t = threadIdx.x;
  const int v = (t < SCG) ? bsum[t] : 0;
  ls[t] = v;
  __syncthreads();
  for (int off = 1; off < 256; off <<= 1) {
    int add = (t >= off) ? ls[t - off] : 0;
    __syncthreads();
    ls[t] += add;
    __syncthreads();
  }
  if (t < SCG) boff[t] = ls[t] - v;
}

__global__ __launch_bounds__(256) void scanC_kernel(const int* __restrict__ T,
                                                    const int* __restrict__ boff,
                                                    int* __restrict__ rowstart,
                                                    int* __restrict__ cursor) {
  const int idx = blockIdx.x * 256 + threadIdx.x;
  if (idx < RAn) {
    int v = T[idx] + boff[blockIdx.x];
    rowstart[idx] = v;
    cursor[idx] = v;
  }
  if (idx == 0) rowstart[RAn] = RFn;
}

// inv[i] = sorted position of original row i (segment-major order)
__global__ void scatter_kernel(const int* __restrict__ ri, int* __restrict__ cursor,
                               int* __restrict__ inv) {
  int i = blockIdx.x * 256 + threadIdx.x;
  if (i < RFn) inv[i] = atomicAdd(&cursor[ri[i]], 1);
}

// ---------------------------------------------------------------------------
// featw5: 32-row block, 128 thr (2 waves). Col-split 64/64 across waves
// PLUS 2 row-tiles per block sharing each B-frag load: B L2 traffic ~1GB.
// Single 33KB LDS buffer -> 4 blocks/CU = 8 waves/CU; async global_load_lds
// staging, cross-block overlap. LN stats via sLN exchange. Records: clean
// 256B-aligned stores + wbuf. Best measured configuration (round 15).
// ---------------------------------------------------------------------------
__global__ __launch_bounds__(128) void featw5_kernel(
    const float* __restrict__ X, const short* __restrict__ fragWS,
    const float* __restrict__ Wa, const float* __restrict__ ba,
    const float* __restrict__ bfeat, const float* __restrict__ gamma,
    const float* __restrict__ beta, const int* __restrict__ inv,
    char* __restrict__ buf, float* __restrict__ wbuf) {
  __shared__ __attribute__((aligned(16))) char lt[32 * ROWPAD];  // 33280 B
  __shared__ float sLN[2][32][2];                                // 512 B

  const int tid = threadIdx.x;
  const int lane = tid & 63;
  const int wv = tid >> 6;     // wave = col half
  const int colb = lane & 15;  // row-in-row-tile for compute
  const int kg = lane >> 4;
  const int t = blockIdx.x;    // rows t*32 .. t*32+31 (always full)

  // -------- stage my 16 rows (async, no VGPR round-trip) --------
  {
    const float* xr = X + (size_t)t * 32 * F1n;
#pragma unroll
    for (int r = 0; r < 16; ++r) {
      const int rr = wv * 16 + r;
      gload_lds16(xr + rr * F1n + lane * 4, &lt[rr * ROWPAD]);
    }
  }

  // per-lane coefs for my col half: ct = wv*4+cc, col = ct*16+colb
  float g_r[4], be_r[4], bi_r[4];
#pragma unroll
  for (int cc = 0; cc < 4; ++cc) {
    const int col = (wv * 4 + cc) * 16 + colb;
    g_r[cc] = gamma[col];
    be_r[cc] = beta[col];
    bi_r[cc] = bfeat[col];
  }
  const float batn = ba[0];

  __syncthreads();  // [A] staging complete for both waves

  // -------- GEMM over K=256: 4 col-tiles x 2 row-tiles, shared bfr --------
  f32x4 acc[2][4];
#pragma unroll
  for (int rt = 0; rt < 2; ++rt)
#pragma unroll
    for (int cc = 0; cc < 4; ++cc) acc[rt][cc] = (f32x4)(0.0f);
  float logit[2] = {0.f, 0.f};

#pragma unroll
  for (int s = 0; s < 8; ++s) {
    short8 bfr[4];
#pragma unroll
    for (int cc = 0; cc < 4; ++cc)
      bfr[cc] = *(const short8*)(fragWS + (((s * 8 + wv * 4 + cc) * 64 + lane) * 8));
    const float4 wa0 = *(const float4*)(Wa + s * 32 + kg * 8);
    const float4 wa1 = *(const float4*)(Wa + s * 32 + kg * 8 + 4);
#pragma unroll
    for (int rt = 0; rt < 2; ++rt) {
      const char* xrow = lt + (rt * 16 + colb) * ROWPAD + s * 128 + kg * 32;
      const float4 x0 = *(const float4*)(xrow);
      const float4 x1 = *(const float4*)(xrow + 16);
      float a0 = fmaxf(x0.x, 0.01f * x0.x);
      float a1 = fmaxf(x0.y, 0.01f * x0.y);
      float a2 = fmaxf(x0.z, 0.01f * x0.z);
      float a3 = fmaxf(x0.w, 0.01f * x0.w);
      float a4 = fmaxf(x1.x, 0.01f * x1.x);
      float a5 = fmaxf(x1.y, 0.01f * x1.y);
      float a6 = fmaxf(x1.z, 0.01f * x1.z);
      float a7 = fmaxf(x1.w, 0.01f * x1.w);
      logit[rt] += a0 * wa0.x + a1 * wa0.y + a2 * wa0.z + a3 * wa0.w +
                   a4 * wa1.x + a5 * wa1.y + a6 * wa1.z + a7 * wa1.w;
      short8 af;
      af[0] = f2bf(a0); af[1] = f2bf(a1); af[2] = f2bf(a2); af[3] = f2bf(a3);
      af[4] = f2bf(a4); af[5] = f2bf(a5); af[6] = f2bf(a6); af[7] = f2bf(a7);
#pragma unroll
      for (int cc = 0; cc < 4; ++cc)
        acc[rt][cc] =
            __builtin_amdgcn_mfma_f32_16x16x32_bf16(af, bfr[cc], acc[rt][cc], 0, 0, 0);
    }
  }

  // -------- per row-tile: wexp, LN partials --------
  float wexp[2];
  float s1v[2][4], s2v[2][4];
#pragma unroll
  for (int rt = 0; rt < 2; ++rt) {
    float lg = logit[rt];
    lg += __shfl_xor(lg, 16);
    lg += __shfl_xor(lg, 32);
    wexp[rt] = __expf(lg + batn);
    if (wv == 0 && lane < 16) wbuf[inv[t * 32 + rt * 16 + colb]] = wexp[rt];

#pragma unroll
    for (int reg = 0; reg < 4; ++reg) {
      s1v[rt][reg] = 0.f;
      s2v[rt][reg] = 0.f;
    }
#pragma unroll
    for (int cc = 0; cc < 4; ++cc)
#pragma unroll
      for (int reg = 0; reg < 4; ++reg) {
        const float v = acc[rt][cc][reg] + bi_r[cc];
        acc[rt][cc][reg] = v;
        s1v[rt][reg] += v;
        s2v[rt][reg] += v * v;
      }
#pragma unroll
    for (int off = 1; off <= 8; off <<= 1)
#pragma unroll
      for (int reg = 0; reg < 4; ++reg) {
        s1v[rt][reg] += __shfl_xor(s1v[rt][reg], off);
        s2v[rt][reg] += __shfl_xor(s2v[rt][reg], off);
      }
    if (colb == 0) {
#pragma unroll
      for (int reg = 0; reg < 4; ++reg) {
        sLN[wv][rt * 16 + kg * 4 + reg][0] = s1v[rt][reg];
        sLN[wv][rt * 16 + kg * 4 + reg][1] = s2v[rt][reg];
      }
    }
  }
  __syncthreads();  // [B] partials ready; both waves done reading X from lt

  // -------- finish LN, write feat*w record image into dead lt --------
#pragma unroll
  for (int rt = 0; rt < 2; ++rt) {
    float w4[4];
#pragma unroll
    for (int reg = 0; reg < 4; ++reg) w4[reg] = __shfl(wexp[rt], kg * 4 + reg);
#pragma unroll
    for (int reg = 0; reg < 4; ++reg) {
      const int row = rt * 16 + kg * 4 + reg;
      const float s1 = s1v[rt][reg] + sLN[wv ^ 1][row][0];
      const float s2 = s2v[rt][reg] + sLN[wv ^ 1][row][1];
      const float mu = s1 * (1.0f / NFn);
      const float var = s2 * (1.0f / NFn) - mu * mu;
      const float rs = rsqrtf(var + LN_EPSn);
#pragma unroll
      for (int cc = 0; cc < 4; ++cc) {
        const float feat = (acc[rt][cc][reg] - mu) * rs * g_r[cc] + be_r[cc];
        ((short*)lt)[row * 136 + (wv * 4 + cc) * 16 + colb] =
            f2bf(feat * w4[reg]);  // 272B LDS row stride (bank spread)
      }
    }
  }
  __syncthreads();  // [C] full records ready

  // -------- 256B-aligned record stores (4 lanes x 64B per row) --------
  {
    const int row = tid >> 2;  // 0..31
    const int p = tid & 3;     // 64B chunk pair
    const int pos = inv[t * 32 + row];
    const char* src = lt + row * 272 + p * 64;
    char* dst = buf + (size_t)pos * RECB + p * 64;
    int4 v0 = *(const int4*)(src);
    int4 v1 = *(const int4*)(src + 16);
    int4 v2 = *(const int4*)(src + 32);
    int4 v3 = *(const int4*)(src + 48);
    *(int4*)(dst) = v0;
    *(int4*)(dst + 16) = v1;
    *(int4*)(dst + 32) = v2;
    *(int4*)(dst + 48) = v3;
  }
}

// ---------------------------------------------------------------------------
// reduce: one wave per segment; records are contiguous per segment. Writes
// every segment (zeros for empty) so no out-memset is needed.
// ---------------------------------------------------------------------------
__global__ __launch_bounds__(256) void reduce_kernel(
    const char* __restrict__ buf, const float* __restrict__ wbuf,
    const int* __restrict__ rowstart, float* __restrict__ out) {
  const int lane = threadIdx.x & 63;
  const int seg = blockIdx.x * 4 + (threadIdx.x >> 6);
  if (seg >= RAn) return;
  const int rb = rowstart[seg], re = rowstart[seg + 1];
  float a0 = 0.f, a1 = 0.f, wsum = 0.f;
  for (int p = rb; p < re; ++p) {
    const char* rec = buf + (size_t)p * RECB;
    unsigned v = *(const unsigned*)(rec + lane * 4);
    a0 += __builtin_bit_cast(float, v << 16);
    a1 += __builtin_bit_cast(float, v & 0xffff0000u);
    wsum += wbuf[p];
  }
  float2 o;
  if (re > rb) {
    o.x = a0 / wsum;
    o.y = a1 / wsum;
  } else {
    o.x = 0.f;
    o.y = 0.f;
  }
  *(float2*)(out + (size_t)seg * NFn + lane * 2) = o;
}

// ---------------------------------------------------------------------------
// Fallback path (small ws): round-1 atomic kernel, known-good.
// ---------------------------------------------------------------------------
__global__ __launch_bounds__(256) void main_atomic(
    const float* __restrict__ X, const short* __restrict__ fragWS,
    const float* __restrict__ Wa, const float* __restrict__ ba,
    const float* __restrict__ bfeat, const float* __restrict__ gamma,
    const float* __restrict__ beta, const int* __restrict__ res_index,
    float* __restrict__ Nacc, float* __restrict__ D) {
  __shared__ short sB[4096 * 8];
  const int tid = threadIdx.x;
  {
    const int4* src = (const int4*)fragWS;
    int4* dst = (int4*)sB;
#pragma unroll 4
    for (int i = tid; i < 4096; i += 256) dst[i] = src[i];
  }
  __syncthreads();
  const int lane = tid & 63;
  const int wv = tid >> 6;
  const int rowbase = blockIdx.x * 128 + wv * 32;
  const int colb = lane & 15;
  const int kg = lane >> 4;
  float g_r[8], be_r[8], bi_r[8];
#pragma unroll
  for (int c = 0; c < 8; ++c) {
    int col = c * 16 + colb;
    g_r[c] = gamma[col];
    be_r[c] = beta[col];
    bi_r[c] = bfeat[col];
  }
  const float batn = ba[0];
  f32x4 acc[2][8];
#pragma unroll
  for (int rt = 0; rt < 2; ++rt)
#pragma unroll
    for (int c = 0; c < 8; ++c) acc[rt][c] = (f32x4)(0.0f);
  float logit[2] = {0.f, 0.f};
  int gr0 = rowbase + colb;
  int gr1 = gr0 + 16;
  long r0 = (gr0 < RFn) ? gr0 : (RFn - 1);
  long r1 = (gr1 < RFn) ? gr1 : (RFn - 1);
  const float* xp0 = X + r0 * F1n + kg * 8;
  const float* xp1 = X + r1 * F1n + kg * 8;
#pragma unroll
  for (int s = 0; s < 8; ++s) {
    short8 bfr[8];
#pragma unroll
    for (int c = 0; c < 8; ++c)
      bfr[c] = *(const short8*)(sB + (((s * 8 + c) * 64 + lane) * 8));
    const float4 wa0 = *(const float4*)(Wa + s * 32 + kg * 8);
    const float4 wa1 = *(const float4*)(Wa + s * 32 + kg * 8 + 4);
#pragma unroll
    for (int rt = 0; rt < 2; ++rt) {
      const float* xp = rt ? xp1 : xp0;
      const float4 x0 = *(const float4*)(xp + s * 32);
      const float4 x1 = *(const float4*)(xp + s * 32 + 4);
      float a0 = fmaxf(x0.x, 0.01f * x0.x);
      float a1 = fmaxf(x0.y, 0.01f * x0.y);
      float a2 = fmaxf(x0.z, 0.01f * x0.z);
      float a3 = fmaxf(x0.w, 0.01f * x0.w);
      float a4 = fmaxf(x1.x, 0.01f * x1.x);
      float a5 = fmaxf(x1.y, 0.01f * x1.y);
      float a6 = fmaxf(x1.z, 0.01f * x1.z);
      float a7 = fmaxf(x1.w, 0.01f * x1.w);
      logit[rt] += a0 * wa0.x + a1 * wa0.y + a2 * wa0.z + a3 * wa0.w +
                   a4 * wa1.x + a5 * wa1.y + a6 * wa1.z + a7 * wa1.w;
      short8 af;
      af[0] = f2bf(a0); af[1] = f2bf(a1); af[2] = f2bf(a2); af[3] = f2bf(a3);
      af[4] = f2bf(a4); af[5] = f2bf(a5); af[6] = f2bf(a6); af[7] = f2bf(a7);
#pragma unroll
      for (int c = 0; c < 8; ++c)
        acc[rt][c] = __builtin_amdgcn_mfma_f32_16x16x32_bf16(af, bfr[c],
                                                             acc[rt][c], 0, 0, 0);
    }
  }
#pragma unroll
  for (int rt = 0; rt < 2; ++rt) {
    float lg = logit[rt];
    lg += __shfl_xor(lg, 16);
    lg += __shfl_xor(lg, 32);
    const float wexp = __expf(lg + batn);
    const int gr = rowbase + rt * 16 + colb;
    const int seg = res_index[(gr < RFn) ? gr : (RFn - 1)];
    if (lane < 16 && gr < RFn) atomicAdd(&D[seg], wexp);
    float w4[4];
    int s4[4], v4[4];
#pragma unroll
    for (int reg = 0; reg < 4; ++reg) {
      int srcl = kg * 4 + reg;
      w4[reg] = __shfl(wexp, srcl);
      s4[reg] = __shfl(seg, srcl);
      v4[reg] = (rowbase + rt * 16 + srcl) < RFn;
    }
    float s1v[4] = {0.f, 0.f, 0.f, 0.f}, s2v[4] = {0.f, 0.f, 0.f, 0.f};
#pragma unroll
    for (int c = 0; c < 8; ++c)
#pragma unroll
      for (int reg = 0; reg < 4; ++reg) {
        float t2 = acc[rt][c][reg] + bi_r[c];
        acc[rt][c][reg] = t2;
        s1v[reg] += t2;
        s2v[reg] += t2 * t2;
      }
#pragma unroll
    for (int off = 1; off <= 8; off <<= 1)
#pragma unroll
      for (int reg = 0; reg < 4; ++reg) {
        s1v[reg] += __shfl_xor(s1v[reg], off);
        s2v[reg] += __shfl_xor(s2v[reg], off);
      }
    float mu[4], rs[4];
#pragma unroll
    for (int reg = 0; reg < 4; ++reg) {
      mu[reg] = s1v[reg] * (1.0f / NFn);
      float var = s2v[reg] * (1.0f / NFn) - mu[reg] * mu[reg];
      rs[reg] = rsqrtf(var + LN_EPSn);
    }
#pragma unroll
    for (int c = 0; c < 8; ++c)
#pragma unroll
      for (int reg = 0; reg < 4; ++reg) {
        if (v4[reg]) {
          float feat = (acc[rt][c][reg] - mu[reg]) * rs[reg] * g_r[c] + be_r[c];
          atomicAdd(Nacc + (size_t)s4[reg] * NFn + c * 16 + colb, feat * w4[reg]);
        }
      }
  }
}

__global__ void div_kernel(float* __restrict__ out, const float* __restrict__ D) {
  int i = blockIdx.x * 256 + threadIdx.x;
  if (i < RAn * NFn) {
    float d = D[i >> 7];
    out[i] = (d > 0.f) ? out[i] / d : 0.f;
  }
}

extern "C" void kernel_launch(void* const* d_in, const int* in_sizes, int n_in,
                              void* d_out, int out_size, void* d_ws, size_t ws_size,
                              hipStream_t stream) {
  const float* X = (const float*)d_in[0];
  const float* Wf = (const float*)d_in[1];
  const float* bfeat = (const float*)d_in[2];
  const float* gamma = (const float*)d_in[3];
  const float* beta = (const float*)d_in[4];
  const float* Wa = (const float*)d_in[5];
  const float* ba = (const float*)d_in[6];
  const int* ri = (const int*)d_in[7];
  float* out = (float*)d_out;

  char* ws = (char*)d_ws;
  short* frag = (short*)ws;              // 65,536 B
  int* hist = (int*)(ws + 65536);        // 200,000 B
  int* T = (int*)(ws + 265536);          // 200,000 B
  int* bsum = (int*)(ws + 465536);       // 784 B
  int* boff = (int*)(ws + 466320);       // 784 B
  int* rowstart = (int*)(ws + 467104);   // 200,004 B
  int* cursor = (int*)(ws + 667108);     // 200,000 B
  int* inv = (int*)(ws + 867108);        // 2,000,000 B
  float* wbuf = (float*)(ws + 2867108);  // 2,000,000 B
  char* buf = ws + 4867328;              // 256-aligned; 128,000,000 B
  const size_t NEED = 4867328ULL + (size_t)RFn * RECB;  // ~132.9 MB

  prep_kernel<<<16, 256, 0, stream>>>(Wf, frag);

  if (ws_size >= NEED) {
    hipMemsetAsync(hist, 0, (size_t)RAn * sizeof(int), stream);
    hist_kernel<<<(RFn + 255) / 256, 256, 0, stream>>>(ri, hist);
    scanA_kernel<<<SCG, 256, 0, stream>>>(hist, T, bsum);
    scanB_kernel<<<1, 256, 0, stream>>>(bsum, boff);
    scanC_kernel<<<SCG, 256, 0, stream>>>(T, boff, rowstart, cursor);
    scatter_kernel<<<(RFn + 255) / 256, 256, 0, stream>>>(ri, cursor, inv);
    featw5_kernel<<<NTILE2, 128, 0, stream>>>(X, frag, Wa, ba, bfeat, gamma,
                                              beta, inv, buf, wbuf);
    reduce_kernel<<<(RAn + 3) / 4, 256, 0, stream>>>(buf, wbuf, rowstart, out);
  } else {
    float* D = (float*)(ws + 65536);
    hipMemsetAsync(out, 0, (size_t)RAn * NFn * sizeof(float), stream);
    hipMemsetAsync(D, 0, (size_t)RAn * sizeof(float), stream);
    main_atomic<<<(RFn + 127) / 128, 256, 0, stream>>>(X, frag, Wa, ba, bfeat,
                                                       gamma, beta, ri, out, D);
    div_kernel<<<(RAn * NFn + 255) / 256, 256, 0, stream>>>(out, D);
  }
}